// Round 1
// baseline (407.482 us; speedup 1.0000x reference)
//
#include <hip/hip_runtime.h>

// Doppler_operatorV2: exploit A_w = kron(I,LM) + kron(LN,I) + eta*I (symmetric).
// Never read the 340MB dense A_w. Three small fp32 kernels; all GEMMs 96x96(xK).
//
// ws layout (floats):
//   GT   [32][96][96]  Gt_s[ni][p]  = wrap((DM @ X_s)[p,ni])
//   HT   [32][96][96]  Ht_s[q][mi]  = wrap((X_s @ DN^T)[mi,q])
//   LM   [96][96]      DM^T DM
//   LN   [96][96]      DN^T DN
//   W    [32][96][96]  W_s[n][m] = pre3[n,m,s] + eta*X_sigma(s)[m,n]
// out[b,c,mi,ni] = (LM V + V LN + eta V)[mi,ni] with V = W^T, sample s=b+8c.

#define MNTOT 9216
#define LSTR  49

#define GT_OFF  0
#define HT_OFF  294912
#define LM_OFF  589824
#define LN_OFF  599040
#define W_OFF   608256

__device__ __forceinline__ float wrapf(float v){
    float r = fmodf(v + 1.0f, 2.0f);
    r = (r < 0.0f) ? r + 2.0f : r;
    return r - 1.0f;
}

// dst[k][j] = src[k*96 + colwin + j],  k in [0,96), j in [0,48)
__device__ __forceinline__ void load_direct(float* dst, const float* __restrict__ src,
                                            int colwin, int tid){
    for(int f = tid; f < 96*48; f += 256){
        int k = f / 48, j = f - 48*k;
        dst[k*LSTR + j] = src[k*96 + colwin + j];
    }
}

// dst[k][j] = src[(rowwin + j)*96 + k],  k in [0,96), j in [0,48)
__device__ __forceinline__ void load_trans(float* dst, const float* __restrict__ src,
                                           int rowwin, int tid){
    for(int f = tid; f < 48*96; f += 256){
        int j = f / 96, k = f - 96*j;
        dst[k*LSTR + j] = src[(rowwin + j)*96 + k];
    }
}

// acc[r][c] += sum_k At[k][r0+r] * Bs[k][c0+c]   (3x3 tile)
__device__ __forceinline__ void gemm96(const float* __restrict__ At, const float* __restrict__ Bs,
                                       float* acc, int r0, int c0){
    #pragma unroll 4
    for(int k = 0; k < 96; k++){
        const float* ar = At + k*LSTR + r0;
        const float* br = Bs + k*LSTR + c0;
        float a0 = ar[0], a1 = ar[1], a2 = ar[2];
        float b0 = br[0], b1 = br[1], b2 = br[2];
        acc[0] = fmaf(a0, b0, acc[0]);
        acc[1] = fmaf(a0, b1, acc[1]);
        acc[2] = fmaf(a0, b2, acc[2]);
        acc[3] = fmaf(a1, b0, acc[3]);
        acc[4] = fmaf(a1, b1, acc[4]);
        acc[5] = fmaf(a1, b2, acc[5]);
        acc[6] = fmaf(a2, b0, acc[6]);
        acc[7] = fmaf(a2, b1, acc[7]);
        acc[8] = fmaf(a2, b2, acc[8]);
    }
}

// --- Kernel 1: Gt_s and Ht_s (wrapped first-difference products), 256 blocks ---
// jid<128: Gt, s=jid>>2, quad=jid&3.  else Ht.
// Gt: C[ni][p] = sum_mi X_s[mi,ni]*DM[p,mi]  -> At=X_s direct, Bs=DM trans
// Ht: C[q][mi] = sum_ni DN[q,ni]*X_s[mi,ni]  -> At=DN trans,  Bs=X_s trans
__global__ __launch_bounds__(256) void k1(const float* __restrict__ x,
                                          const float* __restrict__ DMp,
                                          const float* __restrict__ DNp,
                                          float* __restrict__ ws){
    __shared__ float At[96*LSTR];
    __shared__ float Bs[96*LSTR];
    int jid = blockIdx.x, tid = threadIdx.x;
    int ty = tid >> 4, tx = tid & 15;
    int r0 = ty*3, c0 = tx*3;
    int type = (jid < 128) ? 0 : 1;
    int loc  = (type == 0) ? jid : jid - 128;
    int s    = loc >> 2;
    int quad = loc & 3;
    int rb = (quad >> 1)*48, cb = (quad & 1)*48;
    const float* xs = x + s*MNTOT;

    if(type == 0){ load_direct(At, xs, rb, tid); load_trans(Bs, DMp, cb, tid); }
    else         { load_trans (At, DNp, rb, tid); load_trans(Bs, xs,  cb, tid); }
    __syncthreads();

    float acc[9] = {0.f,0.f,0.f,0.f,0.f,0.f,0.f,0.f,0.f};
    gemm96(At, Bs, acc, r0, c0);

    float* dst = ws + ((type == 0) ? GT_OFF : HT_OFF) + s*MNTOT;
    #pragma unroll
    for(int i = 0; i < 3; i++)
        #pragma unroll
        for(int j = 0; j < 3; j++)
            dst[(rb + r0 + i)*96 + cb + c0 + j] = wrapf(acc[3*i + j]);
}

// --- Kernel 2: W (scrambled pre3 + eta*x^T), plus LM/LN. 136 blocks ---
// jid<128: s_=jid>>2, quad=jid&3.
//   slab p:  At[p][row] = Gt[(rb+row)&31][(3s_+(rb+row)>>5)*96 + p], Bs = DM direct
//   slab i0: At[i0][row] = DN[i0][rb+row] (direct),
//            Bs[i0][m]  = Ht[i0&31][(3s_+(i0>>5))*96 + cb + m]
//   W[n][m] = acc + eta * x[sigma(s_)][m][n],  sigma(s_) = 4*(s_%8)+s_/8
// jid>=128: t=jid-128: 0-3 LM quads, 4-7 LN quads (C = D^T D).
__global__ __launch_bounds__(256) void k2(const float* __restrict__ x,
                                          const float* __restrict__ DMp,
                                          const float* __restrict__ DNp,
                                          const float* __restrict__ eta,
                                          float* __restrict__ ws){
    __shared__ float At[96*LSTR];
    __shared__ float Bs[96*LSTR];
    int jid = blockIdx.x, tid = threadIdx.x;
    int ty = tid >> 4, tx = tid & 15;
    int r0 = ty*3, c0 = tx*3;
    float acc[9] = {0.f,0.f,0.f,0.f,0.f,0.f,0.f,0.f,0.f};

    if(jid < 128){
        int s_ = jid >> 2, quad = jid & 3;
        int rb = (quad >> 1)*48, cb = (quad & 1)*48;
        // slab A: k = p
        for(int f = tid; f < 48*96; f += 256){
            int j = f / 96, k = f - 96*j;
            int n_ = rb + j;
            int sg = n_ & 31, colg = 3*s_ + (n_ >> 5);
            At[k*LSTR + j] = ws[GT_OFF + sg*MNTOT + colg*96 + k];
        }
        load_direct(Bs, DMp, cb, tid);
        __syncthreads();
        gemm96(At, Bs, acc, r0, c0);
        __syncthreads();
        // slab B: k = i0
        load_direct(At, DNp, rb, tid);
        for(int f = tid; f < 96*48; f += 256){
            int k = f / 48, j = f - 48*k;
            int sh = k & 31, colh = 3*s_ + (k >> 5);
            Bs[k*LSTR + j] = ws[HT_OFF + sh*MNTOT + colh*96 + cb + j];
        }
        __syncthreads();
        gemm96(At, Bs, acc, r0, c0);

        float e  = eta[0];
        int  sx  = 4*(s_ & 7) + (s_ >> 3);
        float* Wp = ws + W_OFF + s_*MNTOT;
        #pragma unroll
        for(int i = 0; i < 3; i++)
            #pragma unroll
            for(int j = 0; j < 3; j++){
                int nn = rb + r0 + i, mm = cb + c0 + j;
                Wp[nn*96 + mm] = acc[3*i + j] + e * x[sx*MNTOT + mm*96 + nn];
            }
    } else {
        int t = jid - 128;                 // 0-3: LM, 4-7: LN
        const float* Dp = (t < 4) ? DMp : DNp;
        int quad = t & 3;
        int rb = (quad >> 1)*48, cb = (quad & 1)*48;
        load_direct(At, Dp, rb, tid);
        load_direct(Bs, Dp, cb, tid);
        __syncthreads();
        gemm96(At, Bs, acc, r0, c0);
        float* dst = ws + ((t < 4) ? LM_OFF : LN_OFF);
        #pragma unroll
        for(int i = 0; i < 3; i++)
            #pragma unroll
            for(int j = 0; j < 3; j++)
                dst[(rb + r0 + i)*96 + cb + c0 + j] = acc[3*i + j];
    }
}

// --- Kernel 3: Z = W*LM + LN*W + eta*W ; out[sx][m][n] = Z[n][m]. 128 blocks ---
__global__ __launch_bounds__(256) void k3(const float* __restrict__ eta,
                                          float* __restrict__ ws,
                                          float* __restrict__ out){
    __shared__ float At[96*LSTR];
    __shared__ float Bs[96*LSTR];
    int jid = blockIdx.x, tid = threadIdx.x;
    int s_ = jid >> 2, quad = jid & 3;
    int rb = (quad >> 1)*48, cb = (quad & 1)*48;
    int ty = tid >> 4, tx = tid & 15;
    int r0 = ty*3, c0 = tx*3;
    const float* Wp = ws + W_OFF + s_*MNTOT;
    float acc[9] = {0.f,0.f,0.f,0.f,0.f,0.f,0.f,0.f,0.f};

    // slab p: At[p][row] = W[rb+row][p], Bs[p][m] = LM[p][cb+m]
    load_trans(At, Wp, rb, tid);
    load_direct(Bs, ws + LM_OFF, cb, tid);
    __syncthreads();
    gemm96(At, Bs, acc, r0, c0);
    __syncthreads();
    // slab q: At[q][row] = LN[q][rb+row] (LN symmetric), Bs[q][m] = W[q][cb+m]
    load_direct(At, ws + LN_OFF, rb, tid);
    load_direct(Bs, Wp, cb, tid);
    __syncthreads();
    gemm96(At, Bs, acc, r0, c0);

    float e  = eta[0];
    int  sx  = 4*(s_ & 7) + (s_ >> 3);
    #pragma unroll
    for(int i = 0; i < 3; i++)
        #pragma unroll
        for(int j = 0; j < 3; j++){
            int nn = rb + r0 + i, mm = cb + c0 + j;
            out[sx*MNTOT + mm*96 + nn] = acc[3*i + j] + e * Wp[nn*96 + mm];
        }
}

extern "C" void kernel_launch(void* const* d_in, const int* in_sizes, int n_in,
                              void* d_out, int out_size, void* d_ws, size_t ws_size,
                              hipStream_t stream){
    const float* x   = (const float*)d_in[0];
    const float* eta = (const float*)d_in[1];
    // d_in[2] = A_w : intentionally unused (structure recomputed from DM/DN)
    const float* DMp = (const float*)d_in[3];
    const float* DNp = (const float*)d_in[4];
    float* ws  = (float*)d_ws;
    float* out = (float*)d_out;

    hipLaunchKernelGGL(k1, dim3(256), dim3(256), 0, stream, x, DMp, DNp, ws);
    hipLaunchKernelGGL(k2, dim3(136), dim3(256), 0, stream, x, DMp, DNp, eta, ws);
    hipLaunchKernelGGL(k3, dim3(128), dim3(256), 0, stream, eta, ws, out);
}